// Round 8
// baseline (430.281 us; speedup 1.0000x reference)
//
#include <hip/hip_runtime.h>
#include <stdint.h>

#define NV 6890
#define NJ 24
#define NB_ 256
#define NP 100
#define MP 6912          // GEMM M padded to 108*64

// out element offsets (fp32)
#define OUT_JT   5291520
#define OUT_PLN  5309952

// workspace: float offsets
#define O_JS 0           // 72 floats (J_shaped)
#define O_PW 128         // 400*24 pre-gathered plane weights
// workspace: u16 offset (byte 65536)
#define O_WT 32768       // W~ bf16 [MP][96]

typedef unsigned short u16;
typedef unsigned int u32;
typedef __attribute__((ext_vector_type(8))) short bf16x8;
typedef __attribute__((ext_vector_type(4))) float f32x4;

__device__ __forceinline__ u16 f2bf(float f) {
    u32 u = __float_as_uint(f);
    u += 0x7FFFu + ((u >> 16) & 1u);   // RNE
    return (u16)(u >> 16);
}

__constant__ int c_par[24] = {-1,0,0,0,1,2,3,4,5,6,7,8,9,9,9,12,13,14,16,17,18,19,20,21};

struct Params {
    const float *vt, *sd, *jreg, *lw, *betas, *bpwf, *rback, *rfront,
                *lback, *lfront, *transl, *gor, *ip_bl, *ip_fl, *ip_br, *ip_fr;
    const int *ids_bl, *ids_fl, *ids_br, *ids_fr;
    float* ws;
    u16* wsu;
    float* out;
};

// ---- inline chain helpers (R6-proven math, re-orchestrated) ----------------
// part1: pose fetch + Rodrigues + local transform row -> sTq[jj*12..]
__device__ __forceinline__ void chain_part1(const Params& P, const float* js,
                                            float* sTq, int b, int jj) {
    float px, py, pz;
    const float* bp = P.bpwf;
    if (jj == 0)      { px = P.gor[b*3];   py = P.gor[b*3+1];   pz = P.gor[b*3+2]; }
    else if (jj <= 6) { int o = b*57 + 3*(jj-1); px = bp[o]; py = bp[o+1]; pz = bp[o+2]; }
    else if (jj == 7) { px = P.lback[b*3]; py = P.lback[b*3+1]; pz = P.lback[b*3+2]; }
    else if (jj == 8) { px = P.rback[b*3]; py = P.rback[b*3+1]; pz = P.rback[b*3+2]; }
    else if (jj == 9) { int o = b*57 + 18;     px = bp[o]; py = bp[o+1]; pz = bp[o+2]; }
    else if (jj == 10){ px = P.lfront[b];  py = 0.f; pz = 0.f; }
    else if (jj == 11){ px = P.rfront[b];  py = 0.f; pz = 0.f; }
    else              { int o = b*57 + 21 + 3*(jj-12); px = bp[o]; py = bp[o+1]; pz = bp[o+2]; }
    float ax = px + 1e-8f, ay = py + 1e-8f, az = pz + 1e-8f;
    float ang = sqrtf(ax*ax + ay*ay + az*az);
    float inv = 1.0f / ang;
    float dx = px * inv, dy = py * inv, dz = pz * inv;
    float c = cosf(ang), s = sinf(ang), t = 1.0f - c;
    int p = c_par[jj];
    float rx = js[jj*3+0], ry = js[jj*3+1], rz = js[jj*3+2];
    if (p >= 0) { rx -= js[p*3]; ry -= js[p*3+1]; rz -= js[p*3+2]; }
    sTq[jj*12+0] = 1.f - t*(dy*dy + dz*dz);
    sTq[jj*12+1] = -s*dz + t*dx*dy;
    sTq[jj*12+2] =  s*dy + t*dx*dz;
    sTq[jj*12+3] = rx;
    sTq[jj*12+4] =  s*dz + t*dx*dy;
    sTq[jj*12+5] = 1.f - t*(dx*dx + dz*dz);
    sTq[jj*12+6] = -s*dx + t*dy*dz;
    sTq[jj*12+7] = ry;
    sTq[jj*12+8] = -s*dy + t*dx*dz;
    sTq[jj*12+9] =  s*dx + t*dy*dz;
    sTq[jj*12+10]= 1.f - t*(dx*dx + dy*dy);
    sTq[jj*12+11]= rz;
}
// part2: compose root->jj path (after block sync over sTq) -> g[12]
__device__ __forceinline__ void chain_part2(const float* sTq, float* g, int jj) {
    int path[12]; int d = 0; int cur = jj;
    while (cur >= 0) { path[d++] = cur; cur = c_par[cur]; }
    int r = path[d - 1];
#pragma unroll
    for (int m = 0; m < 12; ++m) g[m] = sTq[r*12+m];
    for (int i = d - 2; i >= 0; --i) {
        int n = path[i];
        float h[12];
#pragma unroll
        for (int row = 0; row < 3; ++row) {
            float a0 = g[row*4+0], a1 = g[row*4+1], a2 = g[row*4+2], a3 = g[row*4+3];
            h[row*4+0] = a0*sTq[n*12+0] + a1*sTq[n*12+4] + a2*sTq[n*12+8];
            h[row*4+1] = a0*sTq[n*12+1] + a1*sTq[n*12+5] + a2*sTq[n*12+9];
            h[row*4+2] = a0*sTq[n*12+2] + a1*sTq[n*12+6] + a2*sTq[n*12+10];
            h[row*4+3] = a0*sTq[n*12+3] + a1*sTq[n*12+7] + a2*sTq[n*12+11] + a3;
        }
#pragma unroll
        for (int m = 0; m < 12; ++m) g[m] = h[m];
    }
}

// ================= D1: J_shaped + W~ build + plane pregather =================
__global__ __launch_bounds__(256) void k_pre(Params P) {
    int bx = blockIdx.x, tid = threadIdx.x;
    if (bx < 24) {
        // J_shaped[j] via flat coalesced streaming, reassociated blend
        int j = bx;
        __shared__ float sb[11];
        __shared__ float r0[256], r1[256], r2[256];
        if (tid < 11) sb[tid] = P.betas[tid];
        __syncthreads();
        float s0 = 0.f, s1 = 0.f, s2 = 0.f;
        const float* jr = P.jreg + (size_t)j * NV;
        for (int q = tid; q < 206700; q += 256) {           // sd part
            float x = P.sd[q];
            int i = q / 30; int cc = q - 30 * i;
            int n = (cc >= 20) ? 2 : ((cc >= 10) ? 1 : 0);
            int l = cc - 10 * n;
            float t = jr[i] * sb[1 + l] * x;
            s0 += (n == 0) ? t : 0.f;
            s1 += (n == 1) ? t : 0.f;
            s2 += (n == 2) ? t : 0.f;
        }
        for (int q = tid; q < 20670; q += 256) {            // vt part
            float x = P.vt[q];
            int i = q / 3; int n = q - 3 * i;
            float t = jr[i] * x;
            s0 += (n == 0) ? t : 0.f;
            s1 += (n == 1) ? t : 0.f;
            s2 += (n == 2) ? t : 0.f;
        }
        r0[tid] = s0; r1[tid] = s1; r2[tid] = s2;
        __syncthreads();
        for (int off = 128; off > 0; off >>= 1) {
            if (tid < off) { r0[tid] += r0[tid+off]; r1[tid] += r1[tid+off]; r2[tid] += r2[tid+off]; }
            __syncthreads();
        }
        if (tid == 0) {
            float b0 = sb[0];
            P.ws[O_JS + j*3 + 0] = b0 * r0[0];
            P.ws[O_JS + j*3 + 1] = b0 * r1[0];
            P.ws[O_JS + j*3 + 2] = b0 * r2[0];
        }
        return;
    }
    if (bx < 51) {
        // W~ build: one vertex per thread; vs recomputed inline (contig reads)
        int v = (bx - 24) * 256 + tid;          // < 6912
        u16 buf[96];
        if (v < NV) {
            float be[11];
#pragma unroll
            for (int l = 0; l < 11; ++l) be[l] = P.betas[l];
            const float* sr = P.sd + (size_t)v * 30;
            const float* vr = P.vt + (size_t)v * 3;
            float vs[3];
#pragma unroll
            for (int n = 0; n < 3; ++n) {
                float acc = vr[n];
#pragma unroll
                for (int l = 0; l < 10; ++l) acc += be[1 + l] * sr[n * 10 + l];
                vs[n] = acc * be[0];
            }
            const float* wr = P.lw + (size_t)v * 24;
#pragma unroll
            for (int j = 0; j < 24; ++j) {
                float w = wr[j];
                buf[j*4+0] = f2bf(w * vs[0]);
                buf[j*4+1] = f2bf(w * vs[1]);
                buf[j*4+2] = f2bf(w * vs[2]);
                buf[j*4+3] = f2bf(w);
            }
        } else {
#pragma unroll
            for (int m = 0; m < 96; ++m) buf[m] = 0;
        }
        uint4* dst = (uint4*)(P.wsu + O_WT + (size_t)v * 96);
        const uint4* src = (const uint4*)buf;
#pragma unroll
        for (int m = 0; m < 12; ++m) dst[m] = src[m];
        return;
    }
    // plane weight pregather: pw[rr*24+j] = lw[ids[p]*24+j]
    int q = (bx - 51) * 256 + tid;
    if (q < 9600) {
        int rr = q / 24, j = q - 24 * rr;       // rr = plane*100+p
        int plane = rr / 100, p = rr - 100 * plane;
        const int* ids = (plane == 0) ? P.ids_bl : (plane == 1) ? P.ids_fl
                       : (plane == 2) ? P.ids_br : P.ids_fr;
        P.ws[O_PW + q] = P.lw[(size_t)ids[p] * 24 + j];
    }
}

// ================= D2: GEMM tiles + planes + jt, all with inline chain ======
#define N_GEMM 1296      // 108 x 12
#define N_PLN  400
#define N_JT   32

__global__ __launch_bounds__(256) void k_mainv2(Params P) {
    __shared__ __align__(16) char smem[28704];
    int bx = blockIdx.x, tid = threadIdx.x;

    if (bx < N_GEMM) {
        // ---- GEMM tile: rows v0.., cols c0..c0+63 of D = W~ @ A~^T ----
        u16*   at_u  = (u16*)smem;                       // [64][96] bf16, 12288B @0
        float* ltile = (float*)smem;                     // [64][66] f32, 16896B @0 (after at dead)
        float* sT    = (float*)(smem + 16896);           // [10][288] f32, 11520B
        float* js    = (float*)(smem + 28416);           // [72]
        int tx = bx % 108, ty = bx / 108;
        int c0 = ty * 64;
        int bstart = c0 / 3;
        int bend = (c0 + 63) / 3;
        int nb = bend - bstart + 1;                      // <= 23
        if (tid < 72) js[tid] = P.ws[O_JS + tid];
        int g = tid / 24, jj = tid - 24 * g;             // g<10 usable (tid<240)
        for (int r = 0; r < 3; ++r) {
            int q = r * 10 + g;
            bool act = (tid < 240) && (q < nb);
            __syncthreads();                             // js ready / prev round consumed
            if (act) chain_part1(P, js, sT + q % 10 * 0 + g * 288, bstart + q, jj);
            __syncthreads();
            if (act) {
                float gg[12];
                chain_part2(sT + g * 288, gg, jj);
                float jx = js[jj*3+0], jy = js[jj*3+1], jz = js[jj*3+2];
                float Av[12];
                Av[0]=gg[0]; Av[1]=gg[1]; Av[2]=gg[2];   Av[3] = gg[3]  - (gg[0]*jx + gg[1]*jy + gg[2]*jz);
                Av[4]=gg[4]; Av[5]=gg[5]; Av[6]=gg[6];   Av[7] = gg[7]  - (gg[4]*jx + gg[5]*jy + gg[6]*jz);
                Av[8]=gg[8]; Av[9]=gg[9]; Av[10]=gg[10]; Av[11]= gg[11] - (gg[8]*jx + gg[9]*jy + gg[10]*jz);
                int b = bstart + q;
#pragma unroll
                for (int m = 0; m < 3; ++m) {
                    int row = b * 3 + m - c0;
                    if (row >= 0 && row < 64) {
#pragma unroll
                        for (int n = 0; n < 4; ++n)
                            at_u[row * 96 + jj * 4 + n] = f2bf(Av[m*4 + n]);
                    }
                }
            }
        }
        __syncthreads();                                 // at_u complete
        const u16* wt = P.wsu + O_WT;
        int lane = tid & 63, wave = tid >> 6;
        int row_in = lane & 15, quad = lane >> 4;
        int v0 = tx * 64 + wave * 16;
        f32x4 acc0 = {0.f,0.f,0.f,0.f}, acc1 = acc0, acc2 = acc0, acc3 = acc0;
#pragma unroll
        for (int kc = 0; kc < 96; kc += 32) {
            bf16x8 a  = *(const bf16x8*)(wt + (size_t)(v0 + row_in) * 96 + kc + quad * 8);
            bf16x8 b0 = *(const bf16x8*)(at_u + ( 0 + row_in) * 96 + kc + quad * 8);
            bf16x8 b1 = *(const bf16x8*)(at_u + (16 + row_in) * 96 + kc + quad * 8);
            bf16x8 b2 = *(const bf16x8*)(at_u + (32 + row_in) * 96 + kc + quad * 8);
            bf16x8 b3 = *(const bf16x8*)(at_u + (48 + row_in) * 96 + kc + quad * 8);
            acc0 = __builtin_amdgcn_mfma_f32_16x16x32_bf16(a, b0, acc0, 0, 0, 0);
            acc1 = __builtin_amdgcn_mfma_f32_16x16x32_bf16(a, b1, acc1, 0, 0, 0);
            acc2 = __builtin_amdgcn_mfma_f32_16x16x32_bf16(a, b2, acc2, 0, 0, 0);
            acc3 = __builtin_amdgcn_mfma_f32_16x16x32_bf16(a, b3, acc3, 0, 0, 0);
        }
        __syncthreads();                                 // all at_u reads done
        int vbase = wave * 16 + quad * 4;
#pragma unroll
        for (int s = 0; s < 4; ++s) {
            f32x4 acc = (s == 0) ? acc0 : (s == 1) ? acc1 : (s == 2) ? acc2 : acc3;
#pragma unroll
            for (int r = 0; r < 4; ++r)
                ltile[(vbase + r) * 66 + s * 16 + row_in] = acc[r];
        }
        __syncthreads();
        int vblk = tx * 64;
        for (int b = bstart; b <= bend; ++b) {
            if (tid < 192) {
                int vl = tid / 3, m = tid - 3 * (tid / 3);
                int cl = b * 3 + m - c0;
                int v = vblk + vl;
                if (cl >= 0 && cl < 64 && v < NV)
                    P.out[((size_t)b * NV + v) * 3 + m] = ltile[vl * 66 + cl] + P.transl[b * 3 + m];
            }
        }
        return;
    }
    if (bx < N_GEMM + N_PLN) {
        // ---- planes: 256 consecutive points, <=2 batches, inline chain ----
        float* sT2 = (float*)smem;                       // [2][288]
        float* sAv = (float*)(smem + 2304);              // [2][288]
        float* js  = (float*)(smem + 4608);              // [72]
        int p0 = (bx - N_GEMM) * 256;
        int b0 = p0 / 400;
        int b1 = (p0 + 255) / 400;
        if (tid < 72) js[tid] = P.ws[O_JS + tid];
        int g = tid >> 5, jj = tid & 31;                 // g=0: b0, g=1: b1
        bool act = (g < 2) && (jj < 24) && (g == 0 || b1 > b0);
        __syncthreads();
        if (act) chain_part1(P, js, sT2 + g * 288, b0 + g, jj);
        __syncthreads();
        if (act) {
            float gg[12];
            chain_part2(sT2 + g * 288, gg, jj);
            float jx = js[jj*3+0], jy = js[jj*3+1], jz = js[jj*3+2];
            float* A = sAv + g * 288 + jj * 12;
            A[0]=gg[0]; A[1]=gg[1]; A[2]=gg[2];   A[3] = gg[3]  - (gg[0]*jx + gg[1]*jy + gg[2]*jz);
            A[4]=gg[4]; A[5]=gg[5]; A[6]=gg[6];   A[7] = gg[7]  - (gg[4]*jx + gg[5]*jy + gg[6]*jz);
            A[8]=gg[8]; A[9]=gg[9]; A[10]=gg[10]; A[11]= gg[11] - (gg[8]*jx + gg[9]*jy + gg[10]*jz);
        }
        __syncthreads();
        int pt = p0 + tid;
        int b = pt / 400;
        int rr = pt - 400 * b;
        const float* w  = P.ws + O_PW + rr * 24;
        const float* Ab = sAv + (b - b0) * 288;
        float T[12];
#pragma unroll
        for (int m = 0; m < 12; ++m) T[m] = 0.f;
#pragma unroll
        for (int j = 0; j < NJ; ++j) {
            float wj = w[j];
#pragma unroll
            for (int m = 0; m < 12; ++m) T[m] += wj * Ab[j * 12 + m];
        }
        int plane = rr / 100, p = rr - 100 * plane;
        const float* ip = (plane == 0) ? P.ip_bl : (plane == 1) ? P.ip_fl
                        : (plane == 2) ? P.ip_br : P.ip_fr;
        size_t io = ((size_t)b * NP + p) * 3;
        float vx = ip[io+0], vy = ip[io+1], vz = ip[io+2];
        float ox = T[0]*vx + T[1]*vy + T[2]*vz  + T[3]  + P.transl[b*3+0];
        float oy = T[4]*vx + T[5]*vy + T[6]*vz  + T[7]  + P.transl[b*3+1];
        float oz = T[8]*vx + T[9]*vy + T[10]*vz + T[11] + P.transl[b*3+2];
        size_t o = (size_t)OUT_PLN + (size_t)pt * 3;
        P.out[o+0] = ox; P.out[o+1] = oy; P.out[o+2] = oz;
        return;
    }
    // ---- jt: 8 batches per block ----
    {
        float* sT = (float*)smem;                        // [8][288]
        float* js = (float*)(smem + 9216);               // [72]
        int bb0 = (bx - N_GEMM - N_PLN) * 8;
        if (tid < 72) js[tid] = P.ws[O_JS + tid];
        int g = tid / 24, jj = tid - 24 * g;
        bool act = (tid < 192);
        __syncthreads();
        if (act) chain_part1(P, js, sT + g * 288, bb0 + g, jj);
        __syncthreads();
        if (act) {
            float gg[12];
            chain_part2(sT + g * 288, gg, jj);
            size_t jo = (size_t)OUT_JT + ((size_t)(bb0 + g) * 24 + jj) * 3;
            P.out[jo+0] = gg[3]; P.out[jo+1] = gg[7]; P.out[jo+2] = gg[11];
        }
    }
}

extern "C" void kernel_launch(void* const* d_in, const int* in_sizes, int n_in,
                              void* d_out, int out_size, void* d_ws, size_t ws_size,
                              hipStream_t stream) {
    Params P;
    P.vt     = (const float*)d_in[0];
    P.sd     = (const float*)d_in[1];
    P.jreg   = (const float*)d_in[2];
    P.lw     = (const float*)d_in[3];
    P.betas  = (const float*)d_in[4];
    P.bpwf   = (const float*)d_in[5];
    P.rback  = (const float*)d_in[6];
    P.rfront = (const float*)d_in[7];
    P.lback  = (const float*)d_in[8];
    P.lfront = (const float*)d_in[9];
    P.transl = (const float*)d_in[10];
    P.gor    = (const float*)d_in[11];
    P.ip_bl  = (const float*)d_in[12];
    P.ip_fl  = (const float*)d_in[13];
    P.ip_br  = (const float*)d_in[14];
    P.ip_fr  = (const float*)d_in[15];
    P.ids_bl = (const int*)d_in[17];
    P.ids_br = (const int*)d_in[18];
    P.ids_fl = (const int*)d_in[19];
    P.ids_fr = (const int*)d_in[20];
    P.ws  = (float*)d_ws;
    P.wsu = (u16*)d_ws;
    P.out = (float*)d_out;

    k_pre   <<<dim3(89), 256, 0, stream>>>(P);
    k_mainv2<<<dim3(N_GEMM + N_PLN + N_JT), 256, 0, stream>>>(P);
}

// Round 9
// 146.749 us; speedup vs baseline: 2.9321x; 2.9321x over previous
//
#include <hip/hip_runtime.h>
#include <stdint.h>

#define NV 6890
#define NJ 24
#define NB_ 256
#define NP 100
#define MP 6912          // GEMM M padded to 108*64

// out element offsets (fp32)
#define OUT_JT   5291520
#define OUT_PLN  5309952

// workspace float offsets
#define O_JP 0           // 24*8*3 = 576 J_shaped partials
#define O_A  576         // 256*24*12 = 73728 fp32 joint transforms
#define O_PW 74304       // 400*24 = 9600 pre-gathered plane weights
// workspace u16 offsets
#define O_WT 169984      // W~ bf16 [MP][96] (byte 339968, 16B aligned)
#define O_AT 833536      // A~ bf16 [768][96] (byte 1667072, 16B aligned)

typedef unsigned short u16;
typedef unsigned int u32;
typedef __attribute__((ext_vector_type(8))) short bf16x8;
typedef __attribute__((ext_vector_type(4))) float f32x4;

__device__ __forceinline__ u16 f2bf(float f) {
    u32 u = __float_as_uint(f);
    u += 0x7FFFu + ((u >> 16) & 1u);   // RNE
    return (u16)(u >> 16);
}

__constant__ int c_par[24] = {-1,0,0,0,1,2,3,4,5,6,7,8,9,9,9,12,13,14,16,17,18,19,20,21};

struct Params {
    const float *vt, *sd, *jreg, *lw, *betas, *bpwf, *rback, *rfront,
                *lback, *lfront, *transl, *gor, *ip_bl, *ip_fl, *ip_br, *ip_fr;
    const int *ids_bl, *ids_fl, *ids_br, *ids_fr;
    float* ws;
    u16* wsu;
    float* out;
};

// ================= D1: W~ build + J_shaped partials =========================
__global__ __launch_bounds__(256) void k_d1(Params P) {
    int bx = blockIdx.x, tid = threadIdx.x;
    if (bx < 27) {
        // W~: one vertex/thread, vs computed inline from contiguous rows
        int v = bx * 256 + tid;                 // < 6912
        u16 buf[96];
        if (v < NV) {
            float be[11];
#pragma unroll
            for (int l = 0; l < 11; ++l) be[l] = P.betas[l];
            const float* sr = P.sd + (size_t)v * 30;
            const float* vr = P.vt + (size_t)v * 3;
            float vs[3];
#pragma unroll
            for (int n = 0; n < 3; ++n) {
                float acc = vr[n];
#pragma unroll
                for (int l = 0; l < 10; ++l) acc += be[1 + l] * sr[n * 10 + l];
                vs[n] = acc * be[0];
            }
            const float* wr = P.lw + (size_t)v * 24;
#pragma unroll
            for (int j = 0; j < 24; ++j) {
                float w = wr[j];
                buf[j*4+0] = f2bf(w * vs[0]);
                buf[j*4+1] = f2bf(w * vs[1]);
                buf[j*4+2] = f2bf(w * vs[2]);
                buf[j*4+3] = f2bf(w);
            }
        } else {
#pragma unroll
            for (int m = 0; m < 96; ++m) buf[m] = 0;
        }
        uint4* dst = (uint4*)(P.wsu + O_WT + (size_t)v * 96);
        const uint4* src = (const uint4*)buf;
#pragma unroll
        for (int m = 0; m < 12; ++m) dst[m] = src[m];
        return;
    }
    // J_shaped partials: (j, slice) = 24 x 8 blocks, ~862 vertices each
    {
        int idx = bx - 27;                      // < 192
        int j = idx >> 3, sl = idx & 7;
        int i0 = sl * 862, i1 = (i0 + 862 < NV) ? i0 + 862 : NV;
        float b0 = P.betas[0];
        float be[10];
#pragma unroll
        for (int l = 0; l < 10; ++l) be[l] = P.betas[1 + l];
        float s0 = 0.f, s1 = 0.f, s2 = 0.f;
        for (int i = i0 + tid; i < i1; i += 256) {
            float w = P.jreg[(size_t)j * NV + i];
            const float* sr = P.sd + (size_t)i * 30;
            const float* vr = P.vt + (size_t)i * 3;
            float c0 = vr[0], c1 = vr[1], c2 = vr[2];
#pragma unroll
            for (int l = 0; l < 10; ++l) {
                c0 += be[l] * sr[l];
                c1 += be[l] * sr[10 + l];
                c2 += be[l] * sr[20 + l];
            }
            s0 += w * (c0 * b0); s1 += w * (c1 * b0); s2 += w * (c2 * b0);
        }
        __shared__ float r0[256], r1[256], r2[256];
        r0[tid] = s0; r1[tid] = s1; r2[tid] = s2;
        __syncthreads();
        for (int off = 128; off > 0; off >>= 1) {
            if (tid < off) { r0[tid] += r0[tid+off]; r1[tid] += r1[tid+off]; r2[tid] += r2[tid+off]; }
            __syncthreads();
        }
        if (tid == 0) {
            P.ws[O_JP + (j*8 + sl)*3 + 0] = r0[0];
            P.ws[O_JP + (j*8 + sl)*3 + 1] = r1[0];
            P.ws[O_JP + (j*8 + sl)*3 + 2] = r2[0];
        }
    }
}

// ================= D2: chain per batch + plane-weight pregather =============
__global__ __launch_bounds__(256) void k_d2(Params P) {
    int bx = blockIdx.x, tid = threadIdx.x;
    if (bx >= NB_) {
        int q = (bx - NB_) * 256 + tid;
        if (q < 9600) {
            int rr = q / 24, j = q - 24 * rr;   // rr = plane*100+p
            int plane = rr / 100, p = rr - 100 * plane;
            const int* ids = (plane == 0) ? P.ids_bl : (plane == 1) ? P.ids_fl
                           : (plane == 2) ? P.ids_br : P.ids_fr;
            P.ws[O_PW + q] = P.lw[(size_t)ids[p] * 24 + j];
        }
        return;
    }
    int b = bx;
    __shared__ float js[72];
    __shared__ float sT[24][12];
    __shared__ float sJ[24][3];
    if (tid < 72) {
        int j = tid / 3, cc = tid - 3 * j;
        float a = 0.f;
#pragma unroll
        for (int s = 0; s < 8; ++s) a += P.ws[O_JP + (j*8 + s)*3 + cc];
        js[tid] = a;
    }
    __syncthreads();
    int j = tid;
    if (j < 24) {
        float px, py, pz;
        const float* bp = P.bpwf;
        if (j == 0)      { px = P.gor[b*3];   py = P.gor[b*3+1];   pz = P.gor[b*3+2]; }
        else if (j <= 6) { int o = b*57 + 3*(j-1); px = bp[o]; py = bp[o+1]; pz = bp[o+2]; }
        else if (j == 7) { px = P.lback[b*3]; py = P.lback[b*3+1]; pz = P.lback[b*3+2]; }
        else if (j == 8) { px = P.rback[b*3]; py = P.rback[b*3+1]; pz = P.rback[b*3+2]; }
        else if (j == 9) { int o = b*57 + 18;     px = bp[o]; py = bp[o+1]; pz = bp[o+2]; }
        else if (j == 10){ px = P.lfront[b];  py = 0.f; pz = 0.f; }
        else if (j == 11){ px = P.rfront[b];  py = 0.f; pz = 0.f; }
        else             { int o = b*57 + 21 + 3*(j-12); px = bp[o]; py = bp[o+1]; pz = bp[o+2]; }
        float ax = px + 1e-8f, ay = py + 1e-8f, az = pz + 1e-8f;
        float ang = sqrtf(ax*ax + ay*ay + az*az);
        float inv = 1.0f / ang;
        float dx = px * inv, dy = py * inv, dz = pz * inv;
        float c = cosf(ang), s = sinf(ang), t = 1.0f - c;
        sJ[j][0] = js[j*3]; sJ[j][1] = js[j*3+1]; sJ[j][2] = js[j*3+2];
        int p = c_par[j];
        float rx = sJ[j][0], ry = sJ[j][1], rz = sJ[j][2];
        if (p >= 0) { rx -= js[p*3]; ry -= js[p*3+1]; rz -= js[p*3+2]; }
        sT[j][0] = 1.f - t*(dy*dy + dz*dz);
        sT[j][1] = -s*dz + t*dx*dy;
        sT[j][2] =  s*dy + t*dx*dz;
        sT[j][3] = rx;
        sT[j][4] =  s*dz + t*dx*dy;
        sT[j][5] = 1.f - t*(dx*dx + dz*dz);
        sT[j][6] = -s*dx + t*dy*dz;
        sT[j][7] = ry;
        sT[j][8] = -s*dy + t*dx*dz;
        sT[j][9] =  s*dx + t*dy*dz;
        sT[j][10]= 1.f - t*(dx*dx + dy*dy);
        sT[j][11]= rz;
    }
    __syncthreads();
    if (j < 24) {
        int path[12]; int d = 0; int cur = j;
        while (cur >= 0) { path[d++] = cur; cur = c_par[cur]; }
        float g[12];
        int r = path[d - 1];
#pragma unroll
        for (int m = 0; m < 12; ++m) g[m] = sT[r][m];
        for (int i = d - 2; i >= 0; --i) {
            int n = path[i];
            float h[12];
#pragma unroll
            for (int row = 0; row < 3; ++row) {
                float a0 = g[row*4+0], a1 = g[row*4+1], a2 = g[row*4+2], a3 = g[row*4+3];
                h[row*4+0] = a0*sT[n][0] + a1*sT[n][4] + a2*sT[n][8];
                h[row*4+1] = a0*sT[n][1] + a1*sT[n][5] + a2*sT[n][9];
                h[row*4+2] = a0*sT[n][2] + a1*sT[n][6] + a2*sT[n][10];
                h[row*4+3] = a0*sT[n][3] + a1*sT[n][7] + a2*sT[n][11] + a3;
            }
#pragma unroll
            for (int m = 0; m < 12; ++m) g[m] = h[m];
        }
        size_t jo = (size_t)OUT_JT + ((size_t)b * 24 + j) * 3;
        P.out[jo+0] = g[3]; P.out[jo+1] = g[7]; P.out[jo+2] = g[11];
        float jx = sJ[j][0], jy = sJ[j][1], jz = sJ[j][2];
        float Av[12];
        Av[0]=g[0]; Av[1]=g[1]; Av[2]=g[2];   Av[3] = g[3]  - (g[0]*jx + g[1]*jy + g[2]*jz);
        Av[4]=g[4]; Av[5]=g[5]; Av[6]=g[6];   Av[7] = g[7]  - (g[4]*jx + g[5]*jy + g[6]*jz);
        Av[8]=g[8]; Av[9]=g[9]; Av[10]=g[10]; Av[11]= g[11] - (g[8]*jx + g[9]*jy + g[10]*jz);
        float* Ab = P.ws + O_A + ((size_t)b * 24 + j) * 12;
#pragma unroll
        for (int m = 0; m < 12; ++m) Ab[m] = Av[m];
        u16* at = P.wsu + O_AT;
#pragma unroll
        for (int m = 0; m < 3; ++m)
#pragma unroll
            for (int n = 0; n < 4; ++n)
                at[(size_t)(b*3 + m) * 96 + j*4 + n] = f2bf(Av[m*4 + n]);
    }
}

// ================= D3: MFMA GEMM (verts) + foot planes ======================
// grid (108, 13). y<12: 64x64 tile of D = W~ (MPx96) @ A~^T (96x768),
// LDS-staged epilogue for contiguous stores. y==12: planes (pregathered w).
__global__ __launch_bounds__(256) void k_d3(Params P) {
    if (blockIdx.y < 12) {
        __shared__ float ltile[64][66];
        const u16* wt = P.wsu + O_WT;
        const u16* at = P.wsu + O_AT;
        int tid = threadIdx.x;
        int lane = tid & 63;
        int wave = tid >> 6;
        int row_in = lane & 15, quad = lane >> 4;
        int v0 = blockIdx.x * 64 + wave * 16;
        int c0 = blockIdx.y * 64;

        f32x4 acc0 = {0.f,0.f,0.f,0.f}, acc1 = acc0, acc2 = acc0, acc3 = acc0;
#pragma unroll
        for (int kc = 0; kc < 96; kc += 32) {
            bf16x8 a  = *(const bf16x8*)(wt + (size_t)(v0 + row_in) * 96 + kc + quad * 8);
            bf16x8 b0 = *(const bf16x8*)(at + (size_t)(c0 +  0 + row_in) * 96 + kc + quad * 8);
            bf16x8 b1 = *(const bf16x8*)(at + (size_t)(c0 + 16 + row_in) * 96 + kc + quad * 8);
            bf16x8 b2 = *(const bf16x8*)(at + (size_t)(c0 + 32 + row_in) * 96 + kc + quad * 8);
            bf16x8 b3 = *(const bf16x8*)(at + (size_t)(c0 + 48 + row_in) * 96 + kc + quad * 8);
            acc0 = __builtin_amdgcn_mfma_f32_16x16x32_bf16(a, b0, acc0, 0, 0, 0);
            acc1 = __builtin_amdgcn_mfma_f32_16x16x32_bf16(a, b1, acc1, 0, 0, 0);
            acc2 = __builtin_amdgcn_mfma_f32_16x16x32_bf16(a, b2, acc2, 0, 0, 0);
            acc3 = __builtin_amdgcn_mfma_f32_16x16x32_bf16(a, b3, acc3, 0, 0, 0);
        }
        int vbase = wave * 16 + quad * 4;
#pragma unroll
        for (int s = 0; s < 4; ++s) {
            f32x4 acc = (s == 0) ? acc0 : (s == 1) ? acc1 : (s == 2) ? acc2 : acc3;
#pragma unroll
            for (int r = 0; r < 4; ++r)
                ltile[vbase + r][s * 16 + row_in] = acc[r];
        }
        __syncthreads();
        int vblk = blockIdx.x * 64;
        int bstart = c0 / 3;
        int bend = (c0 + 63) / 3;
        for (int b = bstart; b <= bend; ++b) {
            if (tid < 192) {
                int vl = tid / 3, m = tid - 3 * (tid / 3);
                int cl = b * 3 + m - c0;
                int v = vblk + vl;
                if (cl >= 0 && cl < 64 && v < NV)
                    P.out[((size_t)b * NV + v) * 3 + m] = ltile[vl][cl] + P.transl[b * 3 + m];
            }
        }
        return;
    }
    // ---- planes ----
    for (int idx = blockIdx.x * 256 + threadIdx.x; idx < NB_ * 400; idx += 108 * 256) {
        int b = idx / 400;
        int rr = idx - 400 * b;              // plane*100 + p
        const float* w  = P.ws + O_PW + rr * 24;
        const float* Ab = P.ws + O_A + (size_t)b * 288;
        float T[12];
#pragma unroll
        for (int m = 0; m < 12; ++m) T[m] = 0.f;
#pragma unroll
        for (int j = 0; j < NJ; ++j) {
            float wj = w[j];
#pragma unroll
            for (int m = 0; m < 12; ++m) T[m] += wj * Ab[j * 12 + m];
        }
        int plane = rr / 100, p = rr - 100 * plane;
        const float* ip = (plane == 0) ? P.ip_bl : (plane == 1) ? P.ip_fl
                        : (plane == 2) ? P.ip_br : P.ip_fr;
        size_t io = ((size_t)b * NP + p) * 3;
        float vx = ip[io+0], vy = ip[io+1], vz = ip[io+2];
        float ox = T[0]*vx + T[1]*vy + T[2]*vz  + T[3]  + P.transl[b*3+0];
        float oy = T[4]*vx + T[5]*vy + T[6]*vz  + T[7]  + P.transl[b*3+1];
        float oz = T[8]*vx + T[9]*vy + T[10]*vz + T[11] + P.transl[b*3+2];
        size_t o = (size_t)OUT_PLN + (size_t)idx * 3;
        P.out[o+0] = ox; P.out[o+1] = oy; P.out[o+2] = oz;
    }
}

extern "C" void kernel_launch(void* const* d_in, const int* in_sizes, int n_in,
                              void* d_out, int out_size, void* d_ws, size_t ws_size,
                              hipStream_t stream) {
    Params P;
    P.vt     = (const float*)d_in[0];
    P.sd     = (const float*)d_in[1];
    P.jreg   = (const float*)d_in[2];
    P.lw     = (const float*)d_in[3];
    P.betas  = (const float*)d_in[4];
    P.bpwf   = (const float*)d_in[5];
    P.rback  = (const float*)d_in[6];
    P.rfront = (const float*)d_in[7];
    P.lback  = (const float*)d_in[8];
    P.lfront = (const float*)d_in[9];
    P.transl = (const float*)d_in[10];
    P.gor    = (const float*)d_in[11];
    P.ip_bl  = (const float*)d_in[12];
    P.ip_fl  = (const float*)d_in[13];
    P.ip_br  = (const float*)d_in[14];
    P.ip_fr  = (const float*)d_in[15];
    // d_in[16] = parents (hardcoded)
    P.ids_bl = (const int*)d_in[17];
    P.ids_br = (const int*)d_in[18];
    P.ids_fl = (const int*)d_in[19];
    P.ids_fr = (const int*)d_in[20];
    P.ws  = (float*)d_ws;
    P.wsu = (u16*)d_ws;
    P.out = (float*)d_out;

    k_d1<<<dim3(27 + 192), 256, 0, stream>>>(P);
    k_d2<<<dim3(NB_ + 38), 256, 0, stream>>>(P);
    k_d3<<<dim3(108, 13), 256, 0, stream>>>(P);
}